// Round 1
// baseline (3232.706 us; speedup 1.0000x reference)
//
#include <hip/hip_runtime.h>
#include <cstdint>

typedef __bf16 bf16x8 __attribute__((ext_vector_type(8)));
typedef float  f32x4  __attribute__((ext_vector_type(4)));

union U4B { uint4 u; bf16x8 b; };
__device__ __forceinline__ bf16x8 as_bf(uint4 u) { U4B x; x.u = u; return x.b; }

// float -> bf16 bits, round-to-nearest-even (finite inputs)
__device__ __forceinline__ unsigned short f2b(float x) {
  unsigned int u = __float_as_uint(x);
  unsigned int r = (u + 0x7fffu + ((u >> 16) & 1u)) >> 16;
  return (unsigned short)r;
}
__device__ __forceinline__ float b2f(unsigned int bits_lo16) {
  return __uint_as_float(bits_lo16 << 16);
}

__device__ __forceinline__ float sigm(float x) {
  // 1/(1+e^-x) = rcp(1 + 2^(-x*log2e))
  float e = __builtin_amdgcn_exp2f(x * -1.4426950408889634f);
  return __builtin_amdgcn_rcpf(1.0f + e);
}
__device__ __forceinline__ float tanh_fast(float x) {
  // 1 - 2/(e^(2x)+1) ; e^(2x) = 2^(x*2*log2e)
  float e = __builtin_amdgcn_exp2f(x * 2.8853900817779268f);
  return 1.0f - 2.0f * __builtin_amdgcn_rcpf(e + 1.0f);
}

// ---------------- prep: build permuted bf16 weight layouts in ws ----------------
// recT [1024 col'][256 k]   : col' = 4u+g  <-> orig col = u + 256g
// kb2  [128 ch][1024 col']  : (kernel + bias) same permutation
// dwT  [128 class][256 k]   : dense_w transposed
__global__ void prep_kernel(const float* __restrict__ rec,
                            const float* __restrict__ kern,
                            const float* __restrict__ bias,
                            const float* __restrict__ dw,
                            unsigned short* __restrict__ recT,
                            unsigned short* __restrict__ kb2,
                            unsigned short* __restrict__ dwT) {
  int id = blockIdx.x * 256 + threadIdx.x;
  if (id < 262144) {                       // 1024*256
    int colp = id >> 8, k = id & 255;
    int u = colp >> 2, g = colp & 3;
    recT[colp * 256 + k] = f2b(rec[k * 1024 + u + 256 * g]);
  } else if (id < 262144 + 131072) {       // 128*1024
    int i = id - 262144;
    int ch = i >> 10, colp = i & 1023;
    int u = colp >> 2, g = colp & 3;
    int oc = u + 256 * g;
    kb2[ch * 1024 + colp] = f2b(kern[ch * 1024 + oc] + bias[oc]);
  } else {                                 // 128*256
    int i = id - 262144 - 131072;
    int cls = i >> 8, k = i & 255;
    dwT[cls * 256 + k] = f2b(dw[k * 128 + cls]);
  }
}

// ---------------- main persistent LSTM kernel ----------------
// grid 64 blocks x 512 threads; block handles 16 batch rows for all 512 steps.
// z^T = recT_frag (A) @ h_frag (B): D col = batch row (lane&15),
// D rows = 4 permuted cols = the 4 gates of unit u = (wid*8+m)*4 + (lane>>4).
__global__ __launch_bounds__(512, 2) void lstm_kernel(
    const unsigned short* __restrict__ recT,
    const unsigned short* __restrict__ kb2,
    const unsigned short* __restrict__ dwT,
    const int* __restrict__ x,
    const float* __restrict__ dense_b,
    float* __restrict__ out) {
  __shared__ unsigned short h_buf[2][16][264];  // bf16 h, padded rows (528B, 16B-aligned)
  __shared__ int   x_lds[16][516];              // staged indices (padded)
  __shared__ float l_lds[16][132];              // logits for softmax

  const int tid   = threadIdx.x;
  const int lane  = tid & 63;
  const int wid   = tid >> 6;      // 0..7
  const int row16 = lane & 15;     // batch row within tile / A-frag row
  const int kg    = lane >> 4;     // 0..3 k-group
  const int rbase = blockIdx.x << 4;

  // stage x slice [16 rows][512 steps]
  for (int e = tid; e < 16 * 512; e += 512) {
    int r = e >> 9, c = e & 511;
    x_lds[r][c] = x[(rbase + r) * 512 + c];
  }
  // zero h(0)
  for (int e = tid; e < 16 * 264; e += 512) (&h_buf[0][0][0])[e] = 0;

  float c_state[8];
#pragma unroll
  for (int m = 0; m < 8; ++m) c_state[m] = 0.0f;

  // per-lane A (recT) base: col' = wid*128 + row16 (+ m*16), k = kg*8 (+ kt*32)
  const unsigned short* recBase = recT + ((wid * 128 + row16) * 256 + kg * 8);

  __syncthreads();

  for (int t = 0; t < 512; ++t) {
    const int cur = t & 1, nxt = cur ^ 1;

    // prefetch K'(idx) gate quads for this step (hidden under GEMM)
    int idx = x_lds[row16][t];
    const unsigned short* kbBase = kb2 + (idx * 1024 + wid * 128 + kg * 4);
    uint2 kq[8];
#pragma unroll
    for (int m = 0; m < 8; ++m) kq[m] = *(const uint2*)(kbBase + m * 16);

    // h fragments (B operand), one per k-tile, reused across all 8 M-tiles
    uint4 hf[8];
#pragma unroll
    for (int k = 0; k < 8; ++k)
      hf[k] = *(const uint4*)&h_buf[cur][row16][k * 32 + kg * 8];

    // GEMM: acc[m][r] = z gates, r = gate (i,f,g,o), for unit (wid*8+m)*4+kg, row row16
    f32x4 acc[8];
#pragma unroll
    for (int m = 0; m < 8; ++m) {
      uint4 af[8];
#pragma unroll
      for (int k = 0; k < 8; ++k)
        af[k] = *(const uint4*)(recBase + m * 4096 + k * 32);
      f32x4 a = {0.f, 0.f, 0.f, 0.f};
#pragma unroll
      for (int k = 0; k < 8; ++k)
        a = __builtin_amdgcn_mfma_f32_16x16x32_bf16(as_bf(af[k]), as_bf(hf[k]), a, 0, 0, 0);
      acc[m] = a;
    }

    // elementwise LSTM update, fully in-register
#pragma unroll
    for (int m = 0; m < 8; ++m) {
      float zi = acc[m][0] + b2f(kq[m].x & 0xffffu);
      float zf = acc[m][1] + b2f(kq[m].x >> 16);
      float zg = acc[m][2] + b2f(kq[m].y & 0xffffu);
      float zo = acc[m][3] + b2f(kq[m].y >> 16);
      float gi = sigm(zi);
      float gf = sigm(zf);
      float gg = tanh_fast(zg);
      float go = sigm(zo);
      float c  = gf * c_state[m] + gi * gg;
      c_state[m] = c;
      float h  = go * tanh_fast(c);
      h_buf[nxt][row16][(wid * 8 + m) * 4 + kg] = f2b(h);
    }
    __syncthreads();
  }

  // ---- final dense (MFMA) + softmax; final h is in h_buf[0] ----
  {
    const unsigned short* dwBase = dwT + ((wid * 16 + row16) * 256 + kg * 8);
    uint4 hf[8];
#pragma unroll
    for (int k = 0; k < 8; ++k)
      hf[k] = *(const uint4*)&h_buf[0][row16][k * 32 + kg * 8];
    f32x4 la = {0.f, 0.f, 0.f, 0.f};
#pragma unroll
    for (int k = 0; k < 8; ++k) {
      uint4 af = *(const uint4*)(dwBase + k * 32);
      la = __builtin_amdgcn_mfma_f32_16x16x32_bf16(as_bf(af), as_bf(hf[k]), la, 0, 0, 0);
    }
#pragma unroll
    for (int r = 0; r < 4; ++r) {
      int cls = wid * 16 + kg * 4 + r;
      l_lds[row16][cls] = la[r] + dense_b[cls];
    }
  }
  __syncthreads();

  {
    int r = tid >> 5, cg = tid & 31;   // 16 rows x 32 col-groups of 4
    float4 v = *(const float4*)&l_lds[r][cg * 4];
    float mx = fmaxf(fmaxf(v.x, v.y), fmaxf(v.z, v.w));
#pragma unroll
    for (int s = 1; s < 32; s <<= 1) mx = fmaxf(mx, __shfl_xor(mx, s));
    const float L2E = 1.4426950408889634f;
    float e0 = __builtin_amdgcn_exp2f((v.x - mx) * L2E);
    float e1 = __builtin_amdgcn_exp2f((v.y - mx) * L2E);
    float e2 = __builtin_amdgcn_exp2f((v.z - mx) * L2E);
    float e3 = __builtin_amdgcn_exp2f((v.w - mx) * L2E);
    float sm = e0 + e1 + e2 + e3;
#pragma unroll
    for (int s = 1; s < 32; s <<= 1) sm += __shfl_xor(sm, s);
    float inv = __builtin_amdgcn_rcpf(sm);
    float4 o = {e0 * inv, e1 * inv, e2 * inv, e3 * inv};
    *(float4*)&out[(rbase + r) * 128 + cg * 4] = o;
  }
}

extern "C" void kernel_launch(void* const* d_in, const int* in_sizes, int n_in,
                              void* d_out, int out_size, void* d_ws, size_t ws_size,
                              hipStream_t stream) {
  const int*   x      = (const int*)d_in[0];    // [1024][512] int32
  const float* kern   = (const float*)d_in[1];  // [128][1024]
  const float* rec    = (const float*)d_in[2];  // [256][1024]
  const float* bias   = (const float*)d_in[3];  // [1024]
  const float* dw     = (const float*)d_in[4];  // [256][128]
  const float* db     = (const float*)d_in[5];  // [128]
  float* outp = (float*)d_out;                  // [1024][128]

  unsigned char* ws = (unsigned char*)d_ws;
  unsigned short* recT = (unsigned short*)(ws);            // 512 KB
  unsigned short* kb2  = (unsigned short*)(ws + 524288);   // 256 KB
  unsigned short* dwT  = (unsigned short*)(ws + 786432);   //  64 KB

  prep_kernel<<<1664, 256, 0, stream>>>(rec, kern, bias, dw, recT, kb2, dwT);
  lstm_kernel<<<64, 512, 0, stream>>>(recT, kb2, dwT, x, db, outp);
}

// Round 2
// 3154.078 us; speedup vs baseline: 1.0249x; 1.0249x over previous
//
#include <hip/hip_runtime.h>
#include <cstdint>

typedef __bf16 bf16x8 __attribute__((ext_vector_type(8)));
typedef float  f32x4  __attribute__((ext_vector_type(4)));

union U4B { uint4 u; bf16x8 b; };
__device__ __forceinline__ bf16x8 as_bf(uint4 u) { U4B x; x.u = u; return x.b; }

// float -> bf16 bits, round-to-nearest-even (finite inputs)
__device__ __forceinline__ unsigned short f2b(float x) {
  unsigned int u = __float_as_uint(x);
  unsigned int r = (u + 0x7fffu + ((u >> 16) & 1u)) >> 16;
  return (unsigned short)r;
}
__device__ __forceinline__ float b2f(unsigned int bits_lo16) {
  return __uint_as_float(bits_lo16 << 16);
}

__device__ __forceinline__ float sigm(float x) {
  float e = __builtin_amdgcn_exp2f(x * -1.4426950408889634f);
  return __builtin_amdgcn_rcpf(1.0f + e);
}
__device__ __forceinline__ float tanh_fast(float x) {
  float e = __builtin_amdgcn_exp2f(x * 2.8853900817779268f);
  return 1.0f - 2.0f * __builtin_amdgcn_rcpf(e + 1.0f);
}

// ---------------- prep: build permuted bf16 weight layouts in ws ----------------
// recT [1024 col'][256 k]   : col' = 4u+g  <-> orig col = u + 256g
// kb2  [128 ch][1024 col']  : (kernel + bias) same permutation
// dwT  [128 class][256 k]   : dense_w transposed
__global__ void prep_kernel(const float* __restrict__ rec,
                            const float* __restrict__ kern,
                            const float* __restrict__ bias,
                            const float* __restrict__ dw,
                            unsigned short* __restrict__ recT,
                            unsigned short* __restrict__ kb2,
                            unsigned short* __restrict__ dwT) {
  int id = blockIdx.x * 256 + threadIdx.x;
  if (id < 262144) {                       // 1024*256
    int colp = id >> 8, k = id & 255;
    int u = colp >> 2, g = colp & 3;
    recT[colp * 256 + k] = f2b(rec[k * 1024 + u + 256 * g]);
  } else if (id < 262144 + 131072) {       // 128*1024
    int i = id - 262144;
    int ch = i >> 10, colp = i & 1023;
    int u = colp >> 2, g = colp & 3;
    int oc = u + 256 * g;
    kb2[ch * 1024 + colp] = f2b(kern[ch * 1024 + oc] + bias[oc]);
  } else {                                 // 128*256
    int i = id - 262144 - 131072;
    int cls = i >> 8, k = i & 255;
    dwT[cls * 256 + k] = f2b(dw[k * 128 + cls]);
  }
}

// ---------------- main persistent LSTM kernel ----------------
// 64 blocks x 1024 threads (16 waves). Block owns 16 batch rows for all 512 steps.
// A (recT) is LOADED INTO REGISTERS ONCE: wave wid owns gate-cols [wid*64, wid*64+64),
// af[m][k] = 128 VGPRs/lane. Per step only h (LDS) + kq (L2) move.
// z^T tile: D col = batch row (lane&15); D rows = 4 permuted cols = gates i,f,g,o
// of unit u = wid*16 + m*4 + (lane>>4).
__global__ __launch_bounds__(1024, 4) void lstm_kernel(
    const unsigned short* __restrict__ recT,
    const unsigned short* __restrict__ kb2,
    const unsigned short* __restrict__ dwT,
    const int* __restrict__ x,
    const float* __restrict__ dense_b,
    float* __restrict__ out) {
  __shared__ unsigned short h_buf[2][16][264];  // bf16 h, padded rows
  __shared__ int   x_lds[16][516];              // staged indices (padded)
  __shared__ float l_lds[16][132];              // logits for softmax

  const int tid   = threadIdx.x;
  const int lane  = tid & 63;
  const int wid   = tid >> 6;      // 0..15
  const int row16 = lane & 15;     // batch row within tile / A-frag row
  const int kg    = lane >> 4;     // 0..3 k-group
  const int rbase = blockIdx.x << 4;

  // stage x slice [16 rows][512 steps]
  for (int e = tid; e < 16 * 512; e += 1024) {
    int r = e >> 9, c = e & 511;
    x_lds[r][c] = x[(rbase + r) * 512 + c];
  }
  // zero h(0)
  for (int e = tid; e < 16 * 264; e += 1024) (&h_buf[0][0][0])[e] = 0;

  // ---- load this wave's A fragments into registers, ONCE ----
  // col' tile base = wid*64 + m*16, A row = row16, k = kt*32 + kg*8 + [0..7]
  const unsigned short* recBase = recT + ((wid * 64 + row16) * 256 + kg * 8);
  uint4 af[4][8];
#pragma unroll
  for (int m = 0; m < 4; ++m)
#pragma unroll
    for (int k = 0; k < 8; ++k)
      af[m][k] = *(const uint4*)(recBase + m * 16 * 256 + k * 32);

  float c_state[4];
#pragma unroll
  for (int m = 0; m < 4; ++m) c_state[m] = 0.0f;

  __syncthreads();

  for (int t = 0; t < 512; ++t) {
    const int cur = t & 1, nxt = cur ^ 1;

    // prefetch K'(idx) gate quads for this step (hidden under GEMM)
    int idx = x_lds[row16][t];
    const unsigned short* kbBase = kb2 + (idx * 1024 + wid * 64 + kg * 4);
    uint2 kq[4];
#pragma unroll
    for (int m = 0; m < 4; ++m) kq[m] = *(const uint2*)(kbBase + m * 16);

    // h fragments (B operand), reused across the 4 M-tiles
    uint4 hf[8];
#pragma unroll
    for (int k = 0; k < 8; ++k)
      hf[k] = *(const uint4*)&h_buf[cur][row16][k * 32 + kg * 8];

    // GEMM from registers: acc[m][r], r = gate (i,f,g,o)
    f32x4 acc[4];
#pragma unroll
    for (int m = 0; m < 4; ++m) {
      f32x4 a = {0.f, 0.f, 0.f, 0.f};
#pragma unroll
      for (int k = 0; k < 8; ++k)
        a = __builtin_amdgcn_mfma_f32_16x16x32_bf16(as_bf(af[m][k]), as_bf(hf[k]), a, 0, 0, 0);
      acc[m] = a;
    }

    // elementwise LSTM update, fully in-register
#pragma unroll
    for (int m = 0; m < 4; ++m) {
      float zi = acc[m][0] + b2f(kq[m].x & 0xffffu);
      float zf = acc[m][1] + b2f(kq[m].x >> 16);
      float zg = acc[m][2] + b2f(kq[m].y & 0xffffu);
      float zo = acc[m][3] + b2f(kq[m].y >> 16);
      float gi = sigm(zi);
      float gf = sigm(zf);
      float gg = tanh_fast(zg);
      float go = sigm(zo);
      float c  = gf * c_state[m] + gi * gg;
      c_state[m] = c;
      float h  = go * tanh_fast(c);
      h_buf[nxt][row16][wid * 16 + m * 4 + kg] = f2b(h);
    }
    __syncthreads();
  }

  // ---- final dense (MFMA) + softmax; final h is in h_buf[0] ----
  if (wid < 8) {
    const unsigned short* dwBase = dwT + ((wid * 16 + row16) * 256 + kg * 8);
    uint4 hf[8];
#pragma unroll
    for (int k = 0; k < 8; ++k)
      hf[k] = *(const uint4*)&h_buf[0][row16][k * 32 + kg * 8];
    f32x4 la = {0.f, 0.f, 0.f, 0.f};
#pragma unroll
    for (int k = 0; k < 8; ++k) {
      uint4 afd = *(const uint4*)(dwBase + k * 32);
      la = __builtin_amdgcn_mfma_f32_16x16x32_bf16(as_bf(afd), as_bf(hf[k]), la, 0, 0, 0);
    }
#pragma unroll
    for (int r = 0; r < 4; ++r) {
      int cls = wid * 16 + kg * 4 + r;
      l_lds[row16][cls] = la[r] + dense_b[cls];
    }
  }
  __syncthreads();

  if (tid < 512) {
    int r = tid >> 5, cg = tid & 31;   // 16 rows x 32 col-groups of 4
    float4 v = *(const float4*)&l_lds[r][cg * 4];
    float mx = fmaxf(fmaxf(v.x, v.y), fmaxf(v.z, v.w));
#pragma unroll
    for (int s = 1; s < 32; s <<= 1) mx = fmaxf(mx, __shfl_xor(mx, s));
    const float L2E = 1.4426950408889634f;
    float e0 = __builtin_amdgcn_exp2f((v.x - mx) * L2E);
    float e1 = __builtin_amdgcn_exp2f((v.y - mx) * L2E);
    float e2 = __builtin_amdgcn_exp2f((v.z - mx) * L2E);
    float e3 = __builtin_amdgcn_exp2f((v.w - mx) * L2E);
    float sm = e0 + e1 + e2 + e3;
#pragma unroll
    for (int s = 1; s < 32; s <<= 1) sm += __shfl_xor(sm, s);
    float inv = __builtin_amdgcn_rcpf(sm);
    float4 o = {e0 * inv, e1 * inv, e2 * inv, e3 * inv};
    *(float4*)&out[(rbase + r) * 128 + cg * 4] = o;
  }
}

extern "C" void kernel_launch(void* const* d_in, const int* in_sizes, int n_in,
                              void* d_out, int out_size, void* d_ws, size_t ws_size,
                              hipStream_t stream) {
  const int*   x      = (const int*)d_in[0];    // [1024][512] int32
  const float* kern   = (const float*)d_in[1];  // [128][1024]
  const float* rec    = (const float*)d_in[2];  // [256][1024]
  const float* bias   = (const float*)d_in[3];  // [1024]
  const float* dw     = (const float*)d_in[4];  // [256][128]
  const float* db     = (const float*)d_in[5];  // [128]
  float* outp = (float*)d_out;                  // [1024][128]

  unsigned char* ws = (unsigned char*)d_ws;
  unsigned short* recT = (unsigned short*)(ws);            // 512 KB
  unsigned short* kb2  = (unsigned short*)(ws + 524288);   // 256 KB
  unsigned short* dwT  = (unsigned short*)(ws + 786432);   //  64 KB

  prep_kernel<<<1664, 256, 0, stream>>>(rec, kern, bias, dw, recT, kb2, dwT);
  lstm_kernel<<<64, 1024, 0, stream>>>(recT, kb2, dwT, x, db, outp);
}

// Round 4
// 2824.491 us; speedup vs baseline: 1.1445x; 1.1167x over previous
//
#include <hip/hip_runtime.h>
#include <cstdint>

typedef __bf16 bf16x8 __attribute__((ext_vector_type(8)));
typedef float  f32x4  __attribute__((ext_vector_type(4)));

union U4B { uint4 u; bf16x8 b; };
__device__ __forceinline__ bf16x8 as_bf(uint4 u) { U4B x; x.u = u; return x.b; }

// float -> bf16 bits, round-to-nearest-even (finite inputs)
__device__ __forceinline__ unsigned short f2b(float x) {
  unsigned int u = __float_as_uint(x);
  unsigned int r = (u + 0x7fffu + ((u >> 16) & 1u)) >> 16;
  return (unsigned short)r;
}
__device__ __forceinline__ float b2f(unsigned int bits_lo16) {
  return __uint_as_float(bits_lo16 << 16);
}

__device__ __forceinline__ float sigm(float x) {
  float e = __builtin_amdgcn_exp2f(x * -1.4426950408889634f);
  return __builtin_amdgcn_rcpf(1.0f + e);
}
__device__ __forceinline__ float tanh_fast(float x) {
  float e = __builtin_amdgcn_exp2f(x * 2.8853900817779268f);
  return 1.0f - 2.0f * __builtin_amdgcn_rcpf(e + 1.0f);
}

// ---------------- prep: build permuted bf16 weight layouts in ws ----------------
// recT [1024 col'][256 k]   : col' = 4u+g  <-> orig col = u + 256g
// kb2  [128 ch][1024 col']  : (kernel + bias) same permutation
// dwT  [128 class][256 k]   : dense_w transposed
__global__ void prep_kernel(const float* __restrict__ rec,
                            const float* __restrict__ kern,
                            const float* __restrict__ bias,
                            const float* __restrict__ dw,
                            unsigned short* __restrict__ recT,
                            unsigned short* __restrict__ kb2,
                            unsigned short* __restrict__ dwT) {
  int id = blockIdx.x * 256 + threadIdx.x;
  if (id < 262144) {                       // 1024*256
    int colp = id >> 8, k = id & 255;
    int u = colp >> 2, g = colp & 3;
    recT[colp * 256 + k] = f2b(rec[k * 1024 + u + 256 * g]);
  } else if (id < 262144 + 131072) {       // 128*1024
    int i = id - 262144;
    int ch = i >> 10, colp = i & 1023;
    int u = colp >> 2, g = colp & 3;
    int oc = u + 256 * g;
    kb2[ch * 1024 + colp] = f2b(kern[ch * 1024 + oc] + bias[oc]);
  } else {                                 // 128*256
    int i = id - 262144 - 131072;
    int cls = i >> 8, k = i & 255;
    dwT[cls * 256 + k] = f2b(dw[k * 128 + cls]);
  }
}

// ---------------- main persistent LSTM kernel ----------------
// 64 blocks x 512 threads (8 waves). Block owns 16 batch rows for all 512 steps.
// Wave wid owns gate-cols [wid*128, wid*128+128) = 8 m-tiles:
//   m 0..3 : A fragments pinned in VGPRs (128 regs)
//   m 4..5 : A fragments in LDS (per-wave-private, linear, 128 KB/block)
//   m 6..7 : A streamed from L2 each step (rotating 3-ahead prefetch)
// z^T tile: D col = batch row (lane&15); D rows = gates i,f,g,o of
// unit u = wid*32 + m*4 + (lane>>4).
__global__ __launch_bounds__(512, 2) void lstm_kernel(
    const unsigned short* __restrict__ recT,
    const unsigned short* __restrict__ kb2,
    const unsigned short* __restrict__ dwT,
    const int* __restrict__ x,
    const float* __restrict__ dense_b,
    float* __restrict__ out) {
  __shared__ uint4 A_lds[2][8][512];            // 128 KB, [slot][k][wid*64+lane]
  __shared__ unsigned short h_buf[2][16][264];  // 16.9 KB bf16 h, padded rows

  const int tid   = threadIdx.x;
  const int lane  = tid & 63;
  const int wid   = tid >> 6;      // 0..7
  const int row16 = lane & 15;     // batch row within tile / A-frag row
  const int kg    = lane >> 4;     // 0..3 k-group
  const int rbase = blockIdx.x << 4;

  // per-lane A base: col' = wid*128 + row16 (+ m*16), k = kg*8 (+ k*32)
  const unsigned short* recBase = recT + ((wid * 128 + row16) * 256 + kg * 8);

  // ---- A regs: m = 0..3, loaded once, pinned (per-component, scalar ties) ----
  uint4 af[4][8];
#pragma unroll
  for (int m = 0; m < 4; ++m)
#pragma unroll
    for (int k = 0; k < 8; ++k) {
      af[m][k] = *(const uint4*)(recBase + m * 4096 + k * 32);
      asm volatile("" : "+v"(af[m][k].x), "+v"(af[m][k].y),
                        "+v"(af[m][k].z), "+v"(af[m][k].w));
    }

  // ---- A LDS: m = 4..5, per-wave-private slots, staged once ----
#pragma unroll
  for (int s = 0; s < 2; ++s)
#pragma unroll
    for (int k = 0; k < 8; ++k)
      A_lds[s][k][wid * 64 + lane] = *(const uint4*)(recBase + (4 + s) * 4096 + k * 32);

  // ---- stream bases: m = 6..7 ----
  const unsigned short* sb6 = recBase + 6 * 4096;
  const unsigned short* sb7 = recBase + 7 * 4096;
  uint4 st6[8], st7[8];
#pragma unroll
  for (int k = 0; k < 3; ++k) {
    st6[k] = *(const uint4*)(sb6 + k * 32);
    st7[k] = *(const uint4*)(sb7 + k * 32);
  }

  // zero h(0)
  for (int e = tid; e < 16 * 264; e += 512) (&h_buf[0][0][0])[e] = 0;

  float c_state[8];
#pragma unroll
  for (int m = 0; m < 8; ++m) c_state[m] = 0.0f;

  const int* xrow = x + (rbase + row16) * 512;
  int idx_cur = xrow[0];

  __syncthreads();

  int cur = 0;
  const unsigned aoff_base = (wid * 64 + lane) * 16;  // byte offset in each [s][k] plane

#pragma unroll 1
  for (int t = 0; t < 512; ++t) {
    // laundered zero offsets: defeat LICM/remat of stream & LDS loads
    unsigned z6 = 0, zL = 0;
    asm volatile("" : "+v"(z6), "+v"(zL));
    const unsigned short* sb6v = sb6 + z6;
    const unsigned short* sb7v = sb7 + z6;
    const unsigned aoff = aoff_base + zL;

    int idx_next = xrow[(t + 1 < 512) ? t + 1 : 511];

    const unsigned short* hrow = &h_buf[cur][row16][0];
    const unsigned short* kb = kb2 + (idx_cur * 1024 + wid * 128 + kg * 4);
    uint2 kq[8];

    f32x4 acc[8];
#pragma unroll
    for (int m = 0; m < 8; ++m) acc[m] = f32x4{0.f, 0.f, 0.f, 0.f};

#pragma unroll
    for (int k = 0; k < 8; ++k) {
      uint4 hf = *(const uint4*)(hrow + k * 32 + kg * 8);
      acc[0] = __builtin_amdgcn_mfma_f32_16x16x32_bf16(as_bf(af[0][k]), as_bf(hf), acc[0], 0, 0, 0);
      acc[1] = __builtin_amdgcn_mfma_f32_16x16x32_bf16(as_bf(af[1][k]), as_bf(hf), acc[1], 0, 0, 0);
      acc[2] = __builtin_amdgcn_mfma_f32_16x16x32_bf16(as_bf(af[2][k]), as_bf(hf), acc[2], 0, 0, 0);
      acc[3] = __builtin_amdgcn_mfma_f32_16x16x32_bf16(as_bf(af[3][k]), as_bf(hf), acc[3], 0, 0, 0);
      uint4 a4 = *(const uint4*)((const char*)A_lds + (0 * 8 + k) * 8192 + aoff);
      acc[4] = __builtin_amdgcn_mfma_f32_16x16x32_bf16(as_bf(a4), as_bf(hf), acc[4], 0, 0, 0);
      uint4 a5 = *(const uint4*)((const char*)A_lds + (1 * 8 + k) * 8192 + aoff);
      acc[5] = __builtin_amdgcn_mfma_f32_16x16x32_bf16(as_bf(a5), as_bf(hf), acc[5], 0, 0, 0);
      acc[6] = __builtin_amdgcn_mfma_f32_16x16x32_bf16(as_bf(st6[k]), as_bf(hf), acc[6], 0, 0, 0);
      acc[7] = __builtin_amdgcn_mfma_f32_16x16x32_bf16(as_bf(st7[k]), as_bf(hf), acc[7], 0, 0, 0);
      // rotating prefetch: pairs (k+3)&7 — k=0..4 feed this step, k=5..7 feed next step
      const int kp = (k + 3) & 7;
      st6[kp] = *(const uint4*)(sb6v + kp * 32);
      st7[kp] = *(const uint4*)(sb7v + kp * 32);
      if (k == 4) {  // issue kq gather with ~4 k-iters of latency cover
#pragma unroll
        for (int m = 0; m < 8; ++m) kq[m] = *(const uint2*)(kb + m * 16);
      }
    }

    // elementwise LSTM update, fully in-register
    unsigned short* hn = &h_buf[cur ^ 1][row16][wid * 32 + kg];
#pragma unroll
    for (int m = 0; m < 8; ++m) {
      float zi = acc[m][0] + b2f(kq[m].x & 0xffffu);
      float zf = acc[m][1] + b2f(kq[m].x >> 16);
      float zg = acc[m][2] + b2f(kq[m].y & 0xffffu);
      float zo = acc[m][3] + b2f(kq[m].y >> 16);
      float gi = sigm(zi);
      float gf = sigm(zf);
      float gg = tanh_fast(zg);
      float go = sigm(zo);
      float c  = gf * c_state[m] + gi * gg;
      c_state[m] = c;
      float h  = go * tanh_fast(c);
      hn[m * 4] = f2b(h);
    }
    __syncthreads();
    cur ^= 1;
    idx_cur = idx_next;
  }

  // ---- final dense (MFMA) + softmax; final h is in h_buf[0] (512 steps, even) ----
  float (*l_lds)[132] = (float (*)[132])A_lds;  // overlay logits onto A_lds region
  {
    const unsigned short* dwBase = dwT + ((wid * 16 + row16) * 256 + kg * 8);
    uint4 hf[8];
#pragma unroll
    for (int k = 0; k < 8; ++k)
      hf[k] = *(const uint4*)&h_buf[0][row16][k * 32 + kg * 8];
    f32x4 la = {0.f, 0.f, 0.f, 0.f};
#pragma unroll
    for (int k = 0; k < 8; ++k) {
      uint4 afd = *(const uint4*)(dwBase + k * 32);
      la = __builtin_amdgcn_mfma_f32_16x16x32_bf16(as_bf(afd), as_bf(hf[k]), la, 0, 0, 0);
    }
#pragma unroll
    for (int r = 0; r < 4; ++r) {
      int cls = wid * 16 + kg * 4 + r;
      l_lds[row16][cls] = la[r] + dense_b[cls];
    }
  }
  __syncthreads();

  {
    int r = tid >> 5, cg = tid & 31;   // 16 rows x 32 col-groups of 4
    float4 v = *(const float4*)&l_lds[r][cg * 4];
    float mx = fmaxf(fmaxf(v.x, v.y), fmaxf(v.z, v.w));
#pragma unroll
    for (int s = 1; s < 32; s <<= 1) mx = fmaxf(mx, __shfl_xor(mx, s));
    const float L2E = 1.4426950408889634f;
    float e0 = __builtin_amdgcn_exp2f((v.x - mx) * L2E);
    float e1 = __builtin_amdgcn_exp2f((v.y - mx) * L2E);
    float e2 = __builtin_amdgcn_exp2f((v.z - mx) * L2E);
    float e3 = __builtin_amdgcn_exp2f((v.w - mx) * L2E);
    float sm = e0 + e1 + e2 + e3;
#pragma unroll
    for (int s = 1; s < 32; s <<= 1) sm += __shfl_xor(sm, s);
    float inv = __builtin_amdgcn_rcpf(sm);
    float4 o = {e0 * inv, e1 * inv, e2 * inv, e3 * inv};
    *(float4*)&out[(rbase + r) * 128 + cg * 4] = o;
  }
}

extern "C" void kernel_launch(void* const* d_in, const int* in_sizes, int n_in,
                              void* d_out, int out_size, void* d_ws, size_t ws_size,
                              hipStream_t stream) {
  const int*   x      = (const int*)d_in[0];    // [1024][512] int32
  const float* kern   = (const float*)d_in[1];  // [128][1024]
  const float* rec    = (const float*)d_in[2];  // [256][1024]
  const float* bias   = (const float*)d_in[3];  // [1024]
  const float* dw     = (const float*)d_in[4];  // [256][128]
  const float* db     = (const float*)d_in[5];  // [128]
  float* outp = (float*)d_out;                  // [1024][128]

  unsigned char* ws = (unsigned char*)d_ws;
  unsigned short* recT = (unsigned short*)(ws);            // 512 KB
  unsigned short* kb2  = (unsigned short*)(ws + 524288);   // 256 KB
  unsigned short* dwT  = (unsigned short*)(ws + 786432);   //  64 KB

  prep_kernel<<<1664, 256, 0, stream>>>(rec, kern, bias, dw, recT, kb2, dwT);
  lstm_kernel<<<64, 512, 0, stream>>>(recT, kb2, dwT, x, db, outp);
}